// Round 1
// baseline (3292.726 us; speedup 1.0000x reference)
//
#include <hip/hip_runtime.h>
#include <hip/hip_bf16.h>

#define NBLK 50
#define HID  16
#define BATCH 16
#define HH 128
#define WW 128
#define PH 136
#define PW 136
#define NCH 2
#define PXS 32                 // shorts per pixel (64 B)
#define ROWE (PW*PXS)          // 4352 shorts = 8704 B per (row, chunk)
#define TAPE 512               // elements per A tap-fragment (64 lanes * 8)
#define SEGPX 72               // staged pixels per wg row-segment (64 out + 8 halo)
#define SEGE (SEGPX*PXS)       // 2304 shorts = 4608 B

typedef __attribute__((ext_vector_type(8))) short short8;
typedef __attribute__((ext_vector_type(4))) float floatx4;

static __device__ __forceinline__ unsigned short f2bf(float f) {
    unsigned int u = __float_as_uint(f);
    unsigned int r = (u + 0x7fffu + ((u >> 16) & 1u)) >> 16;
    return (unsigned short)r;
}

// Bank-conflict swizzle: 16B unit u = px*4+kg stored at u ^ ((px>>1)&7).
// Bijective within each 8-unit (2-pixel) block; makes every 8 consecutive
// lanes of a wave64 ds_read_b128 cover all 32 banks (was 8-way conflicted
// at the 64 B pixel stride). Applied in the GLOBAL feats layout (staging is
// a linear global_load_lds copy) and mirrored on the LDS read address.
static __device__ __forceinline__ int swz(int px, int kg) {
    return (px * 4 + kg) ^ ((px >> 1) & 7);
}

#define GLD16(gp, lp) __builtin_amdgcn_global_load_lds( \
    (__attribute__((address_space(1))) void*)(void*)(gp), \
    (__attribute__((address_space(3))) void*)(lp), 16, 0, 0)

// Stage one 72-px row segment (4608 B contiguous) into LDS with 256 threads.
static __device__ __forceinline__ void stage_seg(const unsigned short* g, unsigned short* l, int tid) {
    const char* gb = (const char*)g;
    char* lb = (char*)l;
    GLD16(gb + tid * 16, lb + (tid & ~63) * 16);
    if (tid < 32) GLD16(gb + 4096 + tid * 16, lb + 4096 + (tid & ~63) * 16);
}

// Pack w1 (fp32 [50][16][51][9][9]) into A-fragment order:
// wbuf[blk][chunk][tap][lane][8], lane: m=lane&15 (hidden ch), k=(lane>>4)*8+j.
// Zero for c>blk (K-padding + write-channel read-safety).
__global__ void prep_w(const float* __restrict__ w1, unsigned short* __restrict__ wbuf) {
    int idx = blockIdx.x * 256 + threadIdx.x;
    const int total = NBLK * NCH * 81 * TAPE;
    if (idx >= total) return;
    int e    = idx & 7;
    int lane = (idx >> 3) & 63;
    int tap  = (idx >> 9) % 81;
    int bc   = idx / (81 * TAPE);
    int ch   = bc & 1, blk = bc >> 1;
    int hc   = lane & 15;
    int c    = ch * 32 + (lane >> 4) * 8 + e;
    float v = 0.f;
    if (c <= blk) v = w1[(((size_t)blk * HID + hc) * (1 + NBLK) + c) * 81 + tap];
    wbuf[idx] = f2bf(v);
}

// Zero only the halo pixels (swizzled unit addresses). Unwritten interior
// channels are safe: weight columns zeroed in wbuf, 0xAA-poison bf16 finite.
__global__ void zero_halo(unsigned short* __restrict__ feats) {
    int t = blockIdx.x * 256 + threadIdx.x;
    const int PPX = 2112;                 // halo px per (b, chunk)
    const int TOT = BATCH * NCH * PPX * 4;
    if (t >= TOT) return;
    int w    = t & 3;
    int rest = t >> 2;
    int p    = rest % PPX;
    int ch   = (rest / PPX) % NCH;
    int b    = rest / (PPX * NCH);
    int row, px;
    if (p < 1088) {                        // rows 0-3, 132-135 (full)
        int r4 = p / 136; px = p % 136;
        row = (r4 < 4) ? r4 : r4 + 128;
    } else {                               // rows 4-131, cols 0-3 & 132-135
        int q = p - 1088;
        row = 4 + (q >> 3);
        int c = q & 7;
        px = (c < 4) ? c : c + 128;
    }
    float4* dst = (float4*)((char*)feats +
        ((((size_t)b * PH + row) * NCH + ch) * ROWE) * 2 + (size_t)swz(px, w) * 16);
    *dst = make_float4(0.f, 0.f, 0.f, 0.f);
}

// Scatter x into feats channel 0, chunk 0 (swizzled layout).
__global__ void init_x(const float* __restrict__ x, unsigned short* __restrict__ feats) {
    int idx = blockIdx.x * 256 + threadIdx.x;
    if (idx >= BATCH * HH * WW) return;
    int xw = idx & (WW - 1);
    int yy = (idx >> 7) & (HH - 1);
    int b  = idx >> 14;
    int pp = xw + 4;
    feats[((((size_t)b * PH + (yy + 4)) * NCH)) * ROWE + (size_t)swz(pp, 0) * 8]
        = f2bf(x[idx]);
}

// One dense block. wg = (b, 8-row strip, 64-px half), 4 waves x 16 px.
// 8-row-deep strips: each staged row serves up to 8 output rows (o-reuse
// doubled vs the old 4-row strips -> ds_reads per MFMA 0.333 -> 0.222).
// A (weights) streamed per-use from L2 (wbuf chunk 83 KB resident); the
// 8-deep ky window doesn't fit in registers and the compiler rematerializes
// anyway. B reads are conflict-free via the unit swizzle.
__global__ __launch_bounds__(256, 2) void block_kern(
    unsigned short* feats, const unsigned short* __restrict__ wbuf,
    const float* __restrict__ b1, const float* __restrict__ w2,
    const float* __restrict__ b2, float* __restrict__ out,
    int blk, int nchunk)
{
    __shared__ __align__(16) unsigned short sB[2][SEGE];

    // XCD-chunked decode: XCD x (bid&7, assuming round-robin dispatch) owns
    // batches 2x..2x+1 (feats slice 2.4 MB < 4 MB XCD L2). Bijective on [0,512).
    const int xcd = blockIdx.x & 7;
    const int i   = blockIdx.x >> 3;        // 0..63
    const int b   = 2 * xcd + (i >> 5);
    const int r5  = i & 31;
    const int s   = r5 >> 1;                // 8-row strip 0..15
    const int h   = r5 & 1;                 // 64-px column half

    const int tid  = threadIdx.x;
    const int lane = tid & 63;
    const int wv   = tid >> 6;
    const int n    = lane & 15;
    const int kg   = lane >> 4;
    const int x0   = wv * 16;               // px offset within the 64-px half

    floatx4 acc[8];
    #pragma unroll
    for (int o = 0; o < 8; ++o)
        acc[o] = (floatx4){0.f, 0.f, 0.f, 0.f};

    const unsigned short* fb = feats + (size_t)b * PH * NCH * ROWE;

    for (int c = 0; c < nchunk; ++c) {
        const unsigned short* wsrc = wbuf + (size_t)(blk * NCH + c) * 81 * TAPE + lane * 8;

        stage_seg(fb + (size_t)((8 * s) * NCH + c) * ROWE + h * (64 * PXS), &sB[0][0], tid);
        __syncthreads();

        #pragma unroll
        for (int step = 0; step < 16; ++step) {
            if (step < 15)
                stage_seg(fb + (size_t)((8 * s + step + 1) * NCH + c) * ROWE + h * (64 * PXS),
                          &sB[(step + 1) & 1][0], tid);

            const unsigned short* bb = &sB[step & 1][0];
            #pragma unroll
            for (int kx = 0; kx < 9; ++kx) {
                const int apx = 64 * h + x0 + kx + n;
                short8 B0 = *(const short8*)(bb + (size_t)(swz(apx, kg) - 256 * h) * 8);
                #pragma unroll
                for (int o = 0; o < 8; ++o) {
                    if (o <= step && step - o <= 8) {
                        short8 A = *(const short8*)(wsrc + (size_t)(((step - o) * 9 + kx) * TAPE));
                        acc[o] = __builtin_amdgcn_mfma_f32_16x16x32_bf16(A, B0, acc[o], 0, 0, 0);
                    }
                }
            }
            __syncthreads();
        }
    }

    // Epilogue: relu(h+b1)·w2, reduce 16 hidden, sigmoid, write out + feats.
    float b1v[4], w2v[4];
    #pragma unroll
    for (int r = 0; r < 4; ++r) {
        b1v[r] = b1[blk * HID + kg * 4 + r];
        w2v[r] = w2[blk * HID + kg * 4 + r];
    }
    const float bb2 = b2[blk];
    const int cw = blk + 1, cchunk = cw >> 5, cidx = cw & 31;

    #pragma unroll
    for (int o = 0; o < 8; ++o) {
        const int yrow = 8 * s + o;
        float p = 0.f;
        #pragma unroll
        for (int r = 0; r < 4; ++r)
            p += fmaxf(acc[o][r] + b1v[r], 0.f) * w2v[r];
        p += __shfl_xor(p, 16, 64);
        p += __shfl_xor(p, 32, 64);
        if (kg == 0) {
            float yv = 1.f / (1.f + __expf(-(p + bb2)));
            int px = 64 * h + x0 + n;
            out[(((size_t)b * NBLK + blk) * HH + yrow) * WW + px] = yv;
            int pp = px + 4;
            feats[(((size_t)b * PH + (yrow + 4)) * NCH + cchunk) * ROWE
                  + (size_t)swz(pp, cidx >> 3) * 8 + (cidx & 7)] = f2bf(yv);
        }
    }
}

extern "C" void kernel_launch(void* const* d_in, const int* in_sizes, int n_in,
                              void* d_out, int out_size, void* d_ws, size_t ws_size,
                              hipStream_t stream) {
    const float* x  = (const float*)d_in[0];
    const float* w1 = (const float*)d_in[1];
    const float* b1 = (const float*)d_in[2];
    const float* w2 = (const float*)d_in[3];
    const float* b2 = (const float*)d_in[4];
    float* out = (float*)d_out;

    unsigned short* feats = (unsigned short*)d_ws;
    size_t feats_bytes = (size_t)BATCH * PH * NCH * ROWE * sizeof(unsigned short); // ~37.9 MB
    unsigned short* wbuf = (unsigned short*)((char*)d_ws + feats_bytes);           // ~8.3 MB

    const int htotal = BATCH * NCH * 2112 * 4;
    zero_halo<<<(htotal + 255) / 256, 256, 0, stream>>>(feats);
    init_x<<<(BATCH * HH * WW + 255) / 256, 256, 0, stream>>>(x, feats);
    const int wtotal = NBLK * NCH * 81 * TAPE;
    prep_w<<<(wtotal + 255) / 256, 256, 0, stream>>>(w1, wbuf);

    for (int blk = 0; blk < NBLK; ++blk) {
        int nchunk = (blk + 32) / 32;  // ceil((blk+1)/32)
        block_kern<<<512, 256, 0, stream>>>(feats, wbuf, b1, w2, b2, out, blk, nchunk);
    }
}

// Round 2
// 1363.951 us; speedup vs baseline: 2.4141x; 2.4141x over previous
//
#include <hip/hip_runtime.h>
#include <hip/hip_bf16.h>

#define NBLK 50
#define HID  16
#define BATCH 16
#define HH 128
#define WW 128
#define PH 136
#define PW 136
#define NCH 2
#define PXS 32                 // shorts per pixel (64 B)
#define ROWE (PW*PXS)          // 4352 shorts = 8704 B per (row, chunk)
#define TAPE 512               // elements per A tap-fragment (64 lanes * 8)

typedef __attribute__((ext_vector_type(8))) short short8;
typedef __attribute__((ext_vector_type(4))) float floatx4;

static __device__ __forceinline__ unsigned short f2bf(float f) {
    unsigned int u = __float_as_uint(f);
    unsigned int r = (u + 0x7fffu + ((u >> 16) & 1u)) >> 16;
    return (unsigned short)r;
}

// Bank-conflict swizzle: 16B unit u = px*4+kg stored at u ^ ((px>>1)&7).
// Bijective within each 8-unit (2-pixel) block; makes every 16 consecutive
// lanes of a wave64 ds_read_b128 cover all 8 bank-start slots (was 8-way
// conflicted at the 64 B pixel stride). Applied in the GLOBAL feats layout
// (staging is a linear global_load_lds copy) and mirrored on the ds_read
// address — both-sides-or-neither.
static __device__ __forceinline__ int swz(int px, int kg) {
    return (px * 4 + kg) ^ ((px >> 1) & 7);
}

#define GLD16(gp, lp) __builtin_amdgcn_global_load_lds( \
    (__attribute__((address_space(1))) void*)(void*)(gp), \
    (__attribute__((address_space(3))) void*)(lp), 16, 0, 0)

// Stage one feats row-chunk (8704 B contiguous) into LDS.
static __device__ __forceinline__ void stage_row(const unsigned short* g, unsigned short* l, int tid) {
    const char* gb = (const char*)g;
    char* lb = (char*)l;
    GLD16(gb + tid * 16,        lb + (tid & ~63) * 16);
    GLD16(gb + 4096 + tid * 16, lb + 4096 + (tid & ~63) * 16);
    if (tid < 32) GLD16(gb + 8192 + tid * 16, lb + 8192 + (tid & ~63) * 16);
}

// Pack w1 (fp32 [50][16][51][9][9]) into A-fragment order:
// wbuf[blk][chunk][tap][lane][8], lane: m=lane&15 (hidden ch), k=(lane>>4)*8+j.
// Zero for c>blk (K-padding + write-channel read-safety).
__global__ void prep_w(const float* __restrict__ w1, unsigned short* __restrict__ wbuf) {
    int idx = blockIdx.x * 256 + threadIdx.x;
    const int total = NBLK * NCH * 81 * TAPE;
    if (idx >= total) return;
    int e    = idx & 7;
    int lane = (idx >> 3) & 63;
    int tap  = (idx >> 9) % 81;
    int bc   = idx / (81 * TAPE);
    int ch   = bc & 1, blk = bc >> 1;
    int hc   = lane & 15;
    int c    = ch * 32 + (lane >> 4) * 8 + e;
    float v = 0.f;
    if (c <= blk) v = w1[(((size_t)blk * HID + hc) * (1 + NBLK) + c) * 81 + tap];
    wbuf[idx] = f2bf(v);
}

// Zero only the halo pixels (swizzled unit addresses). Unwritten interior
// channels are safe: weight columns zeroed in wbuf, 0xAA-poison bf16 finite.
__global__ void zero_halo(unsigned short* __restrict__ feats) {
    int t = blockIdx.x * 256 + threadIdx.x;
    const int PPX = 2112;                 // halo px per (b, chunk)
    const int TOT = BATCH * NCH * PPX * 4;
    if (t >= TOT) return;
    int w    = t & 3;
    int rest = t >> 2;
    int p    = rest % PPX;
    int ch   = (rest / PPX) % NCH;
    int b    = rest / (PPX * NCH);
    int row, px;
    if (p < 1088) {                        // rows 0-3, 132-135 (full)
        int r4 = p / 136; px = p % 136;
        row = (r4 < 4) ? r4 : r4 + 128;
    } else {                               // rows 4-131, cols 0-3 & 132-135
        int q = p - 1088;
        row = 4 + (q >> 3);
        int c = q & 7;
        px = (c < 4) ? c : c + 128;
    }
    float4* dst = (float4*)((char*)feats +
        ((((size_t)b * PH + row) * NCH + ch) * ROWE) * 2 + (size_t)swz(px, w) * 16);
    *dst = make_float4(0.f, 0.f, 0.f, 0.f);
}

// Scatter x into feats channel 0, chunk 0 (swizzled layout).
__global__ void init_x(const float* __restrict__ x, unsigned short* __restrict__ feats) {
    int idx = blockIdx.x * 256 + threadIdx.x;
    if (idx >= BATCH * HH * WW) return;
    int xw = idx & (WW - 1);
    int yy = (idx >> 7) & (HH - 1);
    int b  = idx >> 14;
    int pp = xw + 4;
    feats[((((size_t)b * PH + (yy + 4)) * NCH)) * ROWE + (size_t)swz(pp, 0) * 8]
        = f2bf(x[idx]);
}

// One dense block. wg = (b, 4-row strip), 4 waves x 32 px. Per step r the
// staged input row r serves all (o,ky) with o+ky==r: 4x B-frag reuse.
// A (weights) comes straight from global into a 4-deep ky register window
// (coalesced dwordx4, L2-resident) — LDS carries only B rows, swizzled
// conflict-free.
__global__ __launch_bounds__(256, 2) void block_kern(
    unsigned short* feats, const unsigned short* __restrict__ wbuf,
    const float* __restrict__ b1, const float* __restrict__ w2,
    const float* __restrict__ b2, float* __restrict__ out,
    int blk, int nchunk)
{
    __shared__ __align__(16) unsigned short sB[2][ROWE];

    // XCD-chunked decode: XCD (bid&7, round-robin dispatch) owns batches
    // 2x..2x+1 (feats slice 2.4 MB < 4 MB XCD L2); adjacent strips' shared
    // halo rows become same-XCD L2 hits. Bijective on [0,512).
    const int xcd = blockIdx.x & 7;
    const int i   = blockIdx.x >> 3;        // 0..63
    const int b   = 2 * xcd + (i >> 5);
    const int s   = i & 31;                 // 4-row strip 0..31

    const int tid  = threadIdx.x;
    const int lane = tid & 63;
    const int wv   = tid >> 6;
    const int n    = lane & 15;
    const int kg   = lane >> 4;
    const int x0   = wv * 32;

    floatx4 acc[4][2];
    #pragma unroll
    for (int o = 0; o < 4; ++o)
        #pragma unroll
        for (int t = 0; t < 2; ++t)
            acc[o][t] = (floatx4){0.f, 0.f, 0.f, 0.f};

    const unsigned short* fb = feats + (size_t)b * PH * NCH * ROWE;

    for (int c = 0; c < nchunk; ++c) {
        const unsigned short* wsrc = wbuf + (size_t)(blk * NCH + c) * 81 * TAPE + lane * 8;

        short8 Areg[4][9];
        // prologue: stage row 0, load ky=0 taps into the window
        stage_row(fb + (size_t)((4 * s) * NCH + c) * ROWE, &sB[0][0], tid);
        #pragma unroll
        for (int kx = 0; kx < 9; ++kx)
            Areg[0][kx] = *(const short8*)(wsrc + (size_t)kx * TAPE);
        __syncthreads();

        #pragma unroll
        for (int step = 0; step < 12; ++step) {
            if (step < 11)
                stage_row(fb + (size_t)((4 * s + step + 1) * NCH + c) * ROWE,
                          &sB[(step + 1) & 1][0], tid);

            const unsigned short* bb = &sB[step & 1][0];
            #pragma unroll
            for (int kx = 0; kx < 9; ++kx) {
                short8 B0 = *(const short8*)(bb + (size_t)swz(x0 + kx + n, kg) * 8);
                short8 B1 = *(const short8*)(bb + (size_t)swz(x0 + 16 + kx + n, kg) * 8);
                #pragma unroll
                for (int o = 0; o < 4; ++o) {
                    if (o <= step && step - o <= 8) {
                        acc[o][0] = __builtin_amdgcn_mfma_f32_16x16x32_bf16(
                            Areg[(step - o) & 3][kx], B0, acc[o][0], 0, 0, 0);
                        acc[o][1] = __builtin_amdgcn_mfma_f32_16x16x32_bf16(
                            Areg[(step - o) & 3][kx], B1, acc[o][1], 0, 0, 0);
                    }
                }
            }

            // prefetch next ky's taps into the retiring window slot
            if (step < 8) {
                #pragma unroll
                for (int kx = 0; kx < 9; ++kx)
                    Areg[(step + 1) & 3][kx] =
                        *(const short8*)(wsrc + (size_t)((step + 1) * 9 + kx) * TAPE);
            }
            __syncthreads();
        }
    }

    // Epilogue: relu(h+b1)·w2, reduce 16 hidden, sigmoid, write out + feats.
    float b1v[4], w2v[4];
    #pragma unroll
    for (int r = 0; r < 4; ++r) {
        b1v[r] = b1[blk * HID + kg * 4 + r];
        w2v[r] = w2[blk * HID + kg * 4 + r];
    }
    const float bb2 = b2[blk];
    const int cw = blk + 1, cchunk = cw >> 5, cidx = cw & 31;

    #pragma unroll
    for (int o = 0; o < 4; ++o) {
        const int yrow = 4 * s + o;
        #pragma unroll
        for (int t = 0; t < 2; ++t) {
            float p = 0.f;
            #pragma unroll
            for (int r = 0; r < 4; ++r)
                p += fmaxf(acc[o][t][r] + b1v[r], 0.f) * w2v[r];
            p += __shfl_xor(p, 16, 64);
            p += __shfl_xor(p, 32, 64);
            if (kg == 0) {
                float yv = 1.f / (1.f + __expf(-(p + bb2)));
                int px = x0 + 16 * t + n;
                out[(((size_t)b * NBLK + blk) * HH + yrow) * WW + px] = yv;
                int pp = px + 4;
                feats[(((size_t)b * PH + (yrow + 4)) * NCH + cchunk) * ROWE
                      + (size_t)swz(pp, cidx >> 3) * 8 + (cidx & 7)] = f2bf(yv);
            }
        }
    }
}

extern "C" void kernel_launch(void* const* d_in, const int* in_sizes, int n_in,
                              void* d_out, int out_size, void* d_ws, size_t ws_size,
                              hipStream_t stream) {
    const float* x  = (const float*)d_in[0];
    const float* w1 = (const float*)d_in[1];
    const float* b1 = (const float*)d_in[2];
    const float* w2 = (const float*)d_in[3];
    const float* b2 = (const float*)d_in[4];
    float* out = (float*)d_out;

    unsigned short* feats = (unsigned short*)d_ws;
    size_t feats_bytes = (size_t)BATCH * PH * NCH * ROWE * sizeof(unsigned short); // ~37.9 MB
    unsigned short* wbuf = (unsigned short*)((char*)d_ws + feats_bytes);           // ~8.3 MB

    const int htotal = BATCH * NCH * 2112 * 4;
    zero_halo<<<(htotal + 255) / 256, 256, 0, stream>>>(feats);
    init_x<<<(BATCH * HH * WW + 255) / 256, 256, 0, stream>>>(x, feats);
    const int wtotal = NBLK * NCH * 81 * TAPE;
    prep_w<<<(wtotal + 255) / 256, 256, 0, stream>>>(w1, wbuf);

    for (int blk = 0; blk < NBLK; ++blk) {
        int nchunk = (blk + 32) / 32;  // ceil((blk+1)/32)
        block_kern<<<BATCH * 32, 256, 0, stream>>>(feats, wbuf, b1, w2, b2, out, blk, nchunk);
    }
}